// Round 2
// baseline (351.815 us; speedup 1.0000x reference)
//
#include <hip/hip_runtime.h>
#include <math.h>

// ---- problem constants ----
#define NN      4096   // nodes
#define INF_    512    // in features
#define OUTF    256    // out features
#define NHEAD   4
#define HDIM    64
#define NCHUNK  8      // j-split for fused GEMM

typedef __attribute__((ext_vector_type(8))) short  short8x;
typedef __attribute__((ext_vector_type(4))) float  float4x;

__device__ __forceinline__ unsigned short f2bf(float x) {
    union { float f; unsigned int u; } c; c.f = x;
    unsigned int r = (c.u + 0x7FFFu + ((c.u >> 16) & 1u)) >> 16;
    return (unsigned short)r;
}

// ============================================================
// K1: h = feat @ W^T  (fp32), also write h^T in bf16
// ============================================================
__global__ __launch_bounds__(256) void k_h_gemm(const float* __restrict__ feat,
                                                const float* __restrict__ W,
                                                float* __restrict__ h32,
                                                unsigned short* __restrict__ hT) {
    __shared__ __align__(16) float As[32 * 68];
    __shared__ __align__(16) float Ws[32 * 68];
    const int tid = threadIdx.x;
    const int o0 = blockIdx.x * 64;
    const int m0 = blockIdx.y * 64;
    const int tx = tid & 15;
    const int ty = tid >> 4;
    float acc[4][4];
    #pragma unroll
    for (int a = 0; a < 4; ++a)
        #pragma unroll
        for (int b = 0; b < 4; ++b) acc[a][b] = 0.f;

    for (int kt = 0; kt < INF_; kt += 32) {
        __syncthreads();
        #pragma unroll
        for (int e = 0; e < 8; ++e) {
            int v = tid + e * 256;
            int c = v & 31, r = v >> 5;
            As[c * 68 + r] = feat[(size_t)(m0 + r) * INF_ + kt + c];
            Ws[c * 68 + r] = W[(size_t)(o0 + r) * INF_ + kt + c];
        }
        __syncthreads();
        #pragma unroll
        for (int k = 0; k < 32; ++k) {
            float4x a4 = *(const float4x*)&As[k * 68 + ty * 4];
            float4x w4 = *(const float4x*)&Ws[k * 68 + tx * 4];
            #pragma unroll
            for (int mi = 0; mi < 4; ++mi)
                #pragma unroll
                for (int oi = 0; oi < 4; ++oi)
                    acc[mi][oi] += a4[mi] * w4[oi];
        }
    }
    #pragma unroll
    for (int mi = 0; mi < 4; ++mi) {
        int m = m0 + ty * 4 + mi;
        float4x v; v[0] = acc[mi][0]; v[1] = acc[mi][1]; v[2] = acc[mi][2]; v[3] = acc[mi][3];
        *(float4x*)&h32[(size_t)m * OUTF + o0 + tx * 4] = v;
    }
    #pragma unroll
    for (int oi = 0; oi < 4; ++oi) {
        int o = o0 + tx * 4 + oi;
        ushort4 u;
        u.x = f2bf(acc[0][oi]); u.y = f2bf(acc[1][oi]);
        u.z = f2bf(acc[2][oi]); u.w = f2bf(acc[3][oi]);
        *(ushort4*)&hT[(size_t)o * NN + m0 + ty * 4] = u;
    }
}

// ============================================================
// K1b: es/ed projections + exp tables B=exp(ed), D=exp(0.2 ed)
// ============================================================
__global__ __launch_bounds__(256) void k_edge_proj(const float* __restrict__ h32,
                                                   const float* __restrict__ a,
                                                   float* __restrict__ es,
                                                   float* __restrict__ ed,
                                                   float* __restrict__ Btab,
                                                   float* __restrict__ Dtab) {
    const int n = blockIdx.x;
    const int w = threadIdx.x >> 6;
    const int lane = threadIdx.x & 63;
    float v  = h32[(size_t)n * OUTF + w * HDIM + lane];
    float s1 = v * a[w * 2 * HDIM + lane];
    float s2 = v * a[w * 2 * HDIM + HDIM + lane];
    #pragma unroll
    for (int off = 32; off; off >>= 1) {
        s1 += __shfl_down(s1, off);
        s2 += __shfl_down(s2, off);
    }
    if (lane == 0) {
        es[n * NHEAD + w] = s1;
        ed[n * NHEAD + w] = s2;
        Btab[n * NHEAD + w] = __expf(s2);
        Dtab[n * NHEAD + w] = __expf(0.2f * s2);
    }
}

// ============================================================
// K2a: per row i: den_h = A_h*S1_h + C_h*S2_h where
//   S1 = sum_{masked, es+ed>=0} exp(ed), S2 = sum_{masked, <0} exp(0.2 ed)
// writes coefA = 0.25*exp(es)/den, coefC = 0.25*exp(0.2es)/den
// ============================================================
__global__ __launch_bounds__(256) void k_den(const float* __restrict__ adj,
                                             const float* __restrict__ es,
                                             const float* __restrict__ ed,
                                             const float* __restrict__ Btab,
                                             const float* __restrict__ Dtab,
                                             float* __restrict__ coefA,
                                             float* __restrict__ coefC) {
    __shared__ float rbuf[4][8];
    const int i = blockIdx.x;
    const int tid = threadIdx.x;
    const int w = tid >> 6, lane = tid & 63;
    const float4x esv = ((const float4x*)es)[i];
    const float4x* ed4 = (const float4x*)ed;
    const float4x* B4  = (const float4x*)Btab;
    const float4x* D4  = (const float4x*)Dtab;
    const float4x* arow4 = (const float4x*)(adj + (size_t)i * NN);

    float4x S1 = (float4x){0.f, 0.f, 0.f, 0.f};
    float4x S2 = (float4x){0.f, 0.f, 0.f, 0.f};
    #pragma unroll
    for (int it = 0; it < 4; ++it) {
        int vid = tid + it * 256;
        float4x a4 = arow4[vid];
        #pragma unroll
        for (int u = 0; u < 4; ++u) {
            if (a4[u] > 0.1f) {
                int j = vid * 4 + u;
                float4x e = ed4[j];
                float4x b = B4[j];
                float4x d = D4[j];
                #pragma unroll
                for (int h = 0; h < 4; ++h) {
                    bool pos = (esv[h] + e[h]) >= 0.f;
                    S1[h] += pos ? b[h] : 0.f;
                    S2[h] += pos ? 0.f : d[h];
                }
            }
        }
    }
    #pragma unroll
    for (int off = 32; off; off >>= 1) {
        #pragma unroll
        for (int h = 0; h < 4; ++h) {
            S1[h] += __shfl_xor(S1[h], off);
            S2[h] += __shfl_xor(S2[h], off);
        }
    }
    if (lane == 0) {
        #pragma unroll
        for (int h = 0; h < 4; ++h) { rbuf[w][h] = S1[h]; rbuf[w][4 + h] = S2[h]; }
    }
    __syncthreads();
    if (tid < 4) {
        int h = tid;
        float s1 = rbuf[0][h] + rbuf[1][h] + rbuf[2][h] + rbuf[3][h];
        float s2 = rbuf[0][4 + h] + rbuf[1][4 + h] + rbuf[2][4 + h] + rbuf[3][4 + h];
        float A = __expf(esv[h]);
        float C = __expf(0.2f * esv[h]);
        float den = A * s1 + C * s2;
        float sc = den > 0.f ? 0.25f / den : 0.f;
        coefA[i * NHEAD + h] = A * sc;
        coefC[i * NHEAD + h] = C * sc;
    }
}

// ============================================================
// K2b: fused attention-tile generation + MFMA GEMM
// grid (64 i-tiles, NCHUNK j-chunks); block = 64i x 256o out tile
// p[i][j] computed in regs -> LDS (A-frag layout) -> MFMA vs hT
// ============================================================
__global__ __launch_bounds__(256) void k_fused(const float* __restrict__ adj,
                                               const float* __restrict__ es,
                                               const float* __restrict__ ed,
                                               const float* __restrict__ Btab,
                                               const float* __restrict__ Dtab,
                                               const float* __restrict__ coefA,
                                               const float* __restrict__ coefC,
                                               const unsigned short* __restrict__ hT,
                                               float* __restrict__ partials) {
    __shared__ __align__(16) unsigned short lds_p[64 * 40];
    __shared__ __align__(16) unsigned short lds_h[256 * 40];
    const int tid  = threadIdx.x;
    const int w    = tid >> 6;
    const int lane = tid & 63;
    const int lidx = lane & 15;
    const int quad = lane >> 4;
    const int i0    = blockIdx.x * 64;
    const int kbase = blockIdx.y * (NN / NCHUNK);   // 512-wide j-chunk
    const int il = tid >> 2;          // 0..63 : local i
    const int jg = (tid & 3) * 8;     // 8 j per thread
    const int i  = i0 + il;
    const int hrow = tid >> 3;        // staging role
    const int hkq  = tid & 7;

    const float4x esv = ((const float4x*)es)[i];
    const float4x cA  = ((const float4x*)coefA)[i];
    const float4x cC  = ((const float4x*)coefC)[i];
    const float* arow = adj + (size_t)i * NN + kbase + jg;
    const float4x* ed4 = (const float4x*)ed;
    const float4x* B4  = (const float4x*)Btab;
    const float4x* D4  = (const float4x*)Dtab;

    float4x acc[4][4];
    #pragma unroll
    for (int a = 0; a < 4; ++a)
        #pragma unroll
        for (int b = 0; b < 4; ++b)
            acc[a][b] = (float4x){0.f, 0.f, 0.f, 0.f};

    // double-buffered register prefetch: adj (HBM stream) + hT (L2)
    float4x adv[2][2];
    ushort4 hv[2][8];
    adv[0][0] = *(const float4x*)(arow);
    adv[0][1] = *(const float4x*)(arow + 4);
    #pragma unroll
    for (int it = 0; it < 8; ++it)
        hv[0][it] = *(const ushort4*)&hT[(size_t)(hrow + it * 32) * NN + kbase + hkq * 4];

    const int KSTEPS = (NN / NCHUNK) / 32;   // 16
    for (int ks = 0; ks < KSTEPS; ++ks) {
        const int cur = ks & 1, nxt = cur ^ 1;
        if (ks < KSTEPS - 1) {
            const float* ap = arow + (ks + 1) * 32;
            adv[nxt][0] = *(const float4x*)(ap);
            adv[nxt][1] = *(const float4x*)(ap + 4);
            const int ktn = kbase + (ks + 1) * 32;
            #pragma unroll
            for (int it = 0; it < 8; ++it)
                hv[nxt][it] = *(const ushort4*)&hT[(size_t)(hrow + it * 32) * NN + ktn + hkq * 4];
        }
        // ---- compute 8 p-values (attn row fragment) from registers ----
        const int kt = kbase + ks * 32;
        float pv[8];
        #pragma unroll
        for (int u = 0; u < 8; ++u) {
            float am = (u < 4) ? adv[cur][0][u] : adv[cur][1][u - 4];
            float p = 0.f;
            if (am > 0.1f) {
                int j = kt + jg + u;
                float4x e4 = ed4[j];
                float4x b4 = B4[j];
                float4x d4 = D4[j];
                #pragma unroll
                for (int h = 0; h < 4; ++h)
                    p += ((esv[h] + e4[h]) >= 0.f) ? cA[h] * b4[h] : cC[h] * d4[h];
            }
            pv[u] = p;
        }
        ushort4 p0, p1;
        p0.x = f2bf(pv[0]); p0.y = f2bf(pv[1]); p0.z = f2bf(pv[2]); p0.w = f2bf(pv[3]);
        p1.x = f2bf(pv[4]); p1.y = f2bf(pv[5]); p1.z = f2bf(pv[6]); p1.w = f2bf(pv[7]);

        __syncthreads();   // protect previous iteration's fragment reads
        *(ushort4*)&lds_p[il * 40 + jg]     = p0;
        *(ushort4*)&lds_p[il * 40 + jg + 4] = p1;
        #pragma unroll
        for (int it = 0; it < 8; ++it)
            *(ushort4*)&lds_h[(hrow + it * 32) * 40 + hkq * 4] = hv[cur][it];
        __syncthreads();

        short8x af[4], bfr[4];
        #pragma unroll
        for (int t = 0; t < 4; ++t) {
            af[t]  = *(const short8x*)&lds_p[(t * 16 + lidx) * 40 + quad * 8];
            bfr[t] = *(const short8x*)&lds_h[(w * 64 + t * 16 + lidx) * 40 + quad * 8];
        }
        #pragma unroll
        for (int it = 0; it < 4; ++it)
            #pragma unroll
            for (int nt = 0; nt < 4; ++nt)
                acc[it][nt] = __builtin_amdgcn_mfma_f32_16x16x32_bf16(
                    af[it], bfr[nt], acc[it][nt], 0, 0, 0);
    }
    // epilogue: D layout col = lane&15, row = quad*4 + reg
    float* pbase = partials + (size_t)blockIdx.y * NN * OUTF;
    #pragma unroll
    for (int it = 0; it < 4; ++it)
        #pragma unroll
        for (int nt = 0; nt < 4; ++nt)
            #pragma unroll
            for (int r = 0; r < 4; ++r) {
                int row = i0 + it * 16 + quad * 4 + r;
                int col = w * 64 + nt * 16 + lidx;
                pbase[(size_t)row * OUTF + col] = acc[it][nt][r];
            }
}

// ============================================================
// K5: out = sum_s partials[s] + bias
// ============================================================
__global__ __launch_bounds__(256) void k_reduce_out(const float* __restrict__ partials,
                                                    const float* __restrict__ bias,
                                                    float* __restrict__ out) {
    const int i = blockIdx.x;
    const int n = threadIdx.x;
    float acc = bias[n];
    #pragma unroll
    for (int s = 0; s < NCHUNK; ++s)
        acc += partials[((size_t)s * NN + i) * OUTF + n];
    out[(size_t)i * OUTF + n] = acc;
}

// ============================================================
extern "C" void kernel_launch(void* const* d_in, const int* in_sizes, int n_in,
                              void* d_out, int out_size, void* d_ws, size_t ws_size,
                              hipStream_t stream) {
    const float* feat = (const float*)d_in[0];   // [4096,512]
    const float* adj  = (const float*)d_in[1];   // [4096,4096]
    const float* W    = (const float*)d_in[2];   // [256,512]
    const float* a    = (const float*)d_in[3];   // [4,128]
    const float* bias = (const float*)d_in[4];   // [256]
    float* out = (float*)d_out;                  // [4096,256] fp32

    char* ws = (char*)d_ws;
    float*          h32      = (float*)(ws + 0);                       // 4 MB
    unsigned short* hT       = (unsigned short*)(ws + (4u << 20));     // 2 MB
    float*          es       = (float*)(ws + (6u << 20));              // 64 KB
    float*          ed       = (float*)(ws + (6u << 20) + (64u << 10));
    float*          Btab     = (float*)(ws + (6u << 20) + (128u << 10));
    float*          Dtab     = (float*)(ws + (6u << 20) + (192u << 10));
    float*          coefA    = (float*)(ws + (6u << 20) + (256u << 10));
    float*          coefC    = (float*)(ws + (6u << 20) + (320u << 10));
    float*          partials = (float*)(ws + (8u << 20));              // 32 MB

    k_h_gemm    <<<dim3(4, 64),       256, 0, stream>>>(feat, W, h32, hT);
    k_edge_proj <<<NN,                256, 0, stream>>>(h32, a, es, ed, Btab, Dtab);
    k_den       <<<NN,                256, 0, stream>>>(adj, es, ed, Btab, Dtab, coefA, coefC);
    k_fused     <<<dim3(64, NCHUNK),  256, 0, stream>>>(adj, es, ed, Btab, Dtab, coefA, coefC, hT, partials);
    k_reduce_out<<<NN,                256, 0, stream>>>(partials, bias, out);
}

// Round 3
// 329.066 us; speedup vs baseline: 1.0691x; 1.0691x over previous
//
#include <hip/hip_runtime.h>
#include <math.h>

// ---- problem constants ----
#define NN      4096   // nodes
#define INF_    512    // in features
#define OUTF    256    // out features
#define NHEAD   4
#define HDIM    64

typedef __attribute__((ext_vector_type(8))) short  short8x;
typedef __attribute__((ext_vector_type(4))) float  float4x;

__device__ __forceinline__ unsigned short f2bf(float x) {
    union { float f; unsigned int u; } c; c.f = x;
    unsigned int r = (c.u + 0x7FFFu + ((c.u >> 16) & 1u)) >> 16;
    return (unsigned short)r;
}

// ============================================================
// K0: cast feat and W to bf16
// ============================================================
__global__ __launch_bounds__(256) void k_cast(const float* __restrict__ feat,
                                              const float* __restrict__ W,
                                              unsigned short* __restrict__ featb,
                                              unsigned short* __restrict__ Wb) {
    const int b = blockIdx.x;
    const float* src;
    unsigned short* dst;
    int idx;
    if (b < 2048) { src = feat; dst = featb; idx = b * 1024 + threadIdx.x * 4; }
    else          { src = W;    dst = Wb;    idx = (b - 2048) * 1024 + threadIdx.x * 4; }
    float4x v = *(const float4x*)(src + idx);
    ushort4 u;
    u.x = f2bf(v[0]); u.y = f2bf(v[1]); u.z = f2bf(v[2]); u.w = f2bf(v[3]);
    *(ushort4*)(dst + idx) = u;
}

// ============================================================
// K1: h = feat @ W^T via bf16 MFMA 16x16x32.
// grid 64 blocks (i-tiles of 64); block covers full OUTF=256 (wave w: n in w*64..)
// writes h32 fp32 [node][feat] and hT bf16 [feat][node]
// ============================================================
__global__ __launch_bounds__(256) void k_h_gemm(const unsigned short* __restrict__ featb,
                                                const unsigned short* __restrict__ Wb,
                                                float* __restrict__ h32,
                                                unsigned short* __restrict__ hT) {
    __shared__ __align__(16) unsigned short lds_f[64 * 40];
    __shared__ __align__(16) unsigned short lds_w[256 * 40];
    const int tid  = threadIdx.x;
    const int w    = tid >> 6;
    const int lane = tid & 63;
    const int lidx = lane & 15;
    const int quad = lane >> 4;
    const int i0   = blockIdx.x * 64;
    const int sr = tid >> 2;          // 0..63
    const int skq = (tid & 3) * 8;    // 0,8,16,24

    float4x acc[4][4];
    #pragma unroll
    for (int a = 0; a < 4; ++a)
        #pragma unroll
        for (int b = 0; b < 4; ++b)
            acc[a][b] = (float4x){0.f, 0.f, 0.f, 0.f};

    for (int kt = 0; kt < INF_; kt += 32) {
        __syncthreads();
        // feat tile: 64 rows x 32 k
        *(ushort4*)&lds_f[sr * 40 + skq]     = *(const ushort4*)&featb[(size_t)(i0 + sr) * INF_ + kt + skq];
        *(ushort4*)&lds_f[sr * 40 + skq + 4] = *(const ushort4*)&featb[(size_t)(i0 + sr) * INF_ + kt + skq + 4];
        // W tile: 256 rows x 32 k
        #pragma unroll
        for (int itr = 0; itr < 4; ++itr) {
            int n = itr * 64 + sr;
            *(ushort4*)&lds_w[n * 40 + skq]     = *(const ushort4*)&Wb[(size_t)n * INF_ + kt + skq];
            *(ushort4*)&lds_w[n * 40 + skq + 4] = *(const ushort4*)&Wb[(size_t)n * INF_ + kt + skq + 4];
        }
        __syncthreads();
        short8x af[4], bw[4];
        #pragma unroll
        for (int t = 0; t < 4; ++t) {
            af[t] = *(const short8x*)&lds_f[(t * 16 + lidx) * 40 + quad * 8];
            bw[t] = *(const short8x*)&lds_w[(w * 64 + t * 16 + lidx) * 40 + quad * 8];
        }
        #pragma unroll
        for (int it = 0; it < 4; ++it)
            #pragma unroll
            for (int nt = 0; nt < 4; ++nt)
                acc[it][nt] = __builtin_amdgcn_mfma_f32_16x16x32_bf16(
                    af[it], bw[nt], acc[it][nt], 0, 0, 0);
    }
    // epilogue: D col = lane&15 (n), row = quad*4+r (m)
    #pragma unroll
    for (int it = 0; it < 4; ++it)
        #pragma unroll
        for (int nt = 0; nt < 4; ++nt) {
            int col = w * 64 + nt * 16 + lidx;
            int m0r = i0 + it * 16 + quad * 4;
            #pragma unroll
            for (int r = 0; r < 4; ++r)
                h32[(size_t)(m0r + r) * OUTF + col] = acc[it][nt][r];
            ushort4 u;
            u.x = f2bf(acc[it][nt][0]); u.y = f2bf(acc[it][nt][1]);
            u.z = f2bf(acc[it][nt][2]); u.w = f2bf(acc[it][nt][3]);
            *(ushort4*)&hT[(size_t)col * NN + m0r] = u;
        }
}

// ============================================================
// K1b: es/ed projections + exp tables B=exp(ed), D=exp(0.2 ed)
// ============================================================
__global__ __launch_bounds__(256) void k_edge_proj(const float* __restrict__ h32,
                                                   const float* __restrict__ a,
                                                   float* __restrict__ es,
                                                   float* __restrict__ ed,
                                                   float* __restrict__ Btab,
                                                   float* __restrict__ Dtab) {
    const int n = blockIdx.x;
    const int w = threadIdx.x >> 6;
    const int lane = threadIdx.x & 63;
    float v  = h32[(size_t)n * OUTF + w * HDIM + lane];
    float s1 = v * a[w * 2 * HDIM + lane];
    float s2 = v * a[w * 2 * HDIM + HDIM + lane];
    #pragma unroll
    for (int off = 32; off; off >>= 1) {
        s1 += __shfl_down(s1, off);
        s2 += __shfl_down(s2, off);
    }
    if (lane == 0) {
        es[n * NHEAD + w] = s1;
        ed[n * NHEAD + w] = s2;
        Btab[n * NHEAD + w] = __expf(s2);
        Dtab[n * NHEAD + w] = __expf(0.2f * s2);
    }
}

// ============================================================
// K2: per row: den from tables (no inner exp), then write bf16 attn row.
// adj row cached in registers across both passes -> adj read once.
// ============================================================
__global__ __launch_bounds__(256) void k_attn(const float* __restrict__ adj,
                                              const float* __restrict__ es,
                                              const float* __restrict__ ed,
                                              const float* __restrict__ Btab,
                                              const float* __restrict__ Dtab,
                                              unsigned short* __restrict__ attn) {
    __shared__ float rbuf[4][8];
    const int i = blockIdx.x;
    const int tid = threadIdx.x;
    const int w = tid >> 6, lane = tid & 63;
    const float4x esv = ((const float4x*)es)[i];
    const float4x* ed4 = (const float4x*)ed;
    const float4x* B4  = (const float4x*)Btab;
    const float4x* D4  = (const float4x*)Dtab;
    const float4x* arow4 = (const float4x*)(adj + (size_t)i * NN);

    // ---- P1: masked sums (adj row -> registers) ----
    float4x adjv[4];
    float4x S1 = (float4x){0.f, 0.f, 0.f, 0.f};
    float4x S2 = (float4x){0.f, 0.f, 0.f, 0.f};
    #pragma unroll
    for (int it = 0; it < 4; ++it) {
        int vid = tid + it * 256;
        adjv[it] = arow4[vid];
        #pragma unroll
        for (int u = 0; u < 4; ++u) {
            if (adjv[it][u] > 0.1f) {
                int j = vid * 4 + u;
                float4x e = ed4[j];
                float4x b = B4[j];
                float4x d = D4[j];
                #pragma unroll
                for (int h = 0; h < 4; ++h) {
                    bool pos = (esv[h] + e[h]) >= 0.f;
                    S1[h] += pos ? b[h] : 0.f;
                    S2[h] += pos ? 0.f : d[h];
                }
            }
        }
    }
    #pragma unroll
    for (int off = 32; off; off >>= 1) {
        #pragma unroll
        for (int h = 0; h < 4; ++h) {
            S1[h] += __shfl_xor(S1[h], off);
            S2[h] += __shfl_xor(S2[h], off);
        }
    }
    if (lane == 0) {
        #pragma unroll
        for (int h = 0; h < 4; ++h) { rbuf[w][h] = S1[h]; rbuf[w][4 + h] = S2[h]; }
    }
    __syncthreads();
    float cA[4], cC[4];
    #pragma unroll
    for (int h = 0; h < 4; ++h) {
        float s1 = rbuf[0][h] + rbuf[1][h] + rbuf[2][h] + rbuf[3][h];
        float s2 = rbuf[0][4 + h] + rbuf[1][4 + h] + rbuf[2][4 + h] + rbuf[3][4 + h];
        float A = __expf(esv[h]);
        float C = __expf(0.2f * esv[h]);
        float den = A * s1 + C * s2;
        float sc = den > 0.f ? 0.25f / den : 0.f;
        cA[h] = A * sc;
        cC[h] = C * sc;
    }

    // ---- P2: write attn row (bf16) ----
    #pragma unroll
    for (int it = 0; it < 4; ++it) {
        int vid = tid + it * 256;
        ushort4 o;
        unsigned short* op = (unsigned short*)&o;
        #pragma unroll
        for (int u = 0; u < 4; ++u) {
            float p = 0.f;
            if (adjv[it][u] > 0.1f) {
                int j = vid * 4 + u;
                float4x e = ed4[j];
                float4x b = B4[j];
                float4x d = D4[j];
                #pragma unroll
                for (int h = 0; h < 4; ++h)
                    p += ((esv[h] + e[h]) >= 0.f) ? cA[h] * b[h] : cC[h] * d[h];
            }
            op[u] = f2bf(p);
        }
        *(ushort4*)&attn[(size_t)i * NN + vid * 4] = o;
    }
}

// ============================================================
// K4: partials[s] = attn[:, ks] @ h[ks, :]  (bf16 MFMA 16x16x32)
// grid (64 i-tiles, 4 k-splits); block tile 64i x 256n
// ============================================================
__global__ __launch_bounds__(256) void k_out_gemm(const unsigned short* __restrict__ attn,
                                                  const unsigned short* __restrict__ hT,
                                                  float* __restrict__ partials) {
    __shared__ __align__(16) unsigned short lds_a[64 * 40];
    __shared__ __align__(16) unsigned short lds_h[256 * 40];
    const int tid  = threadIdx.x;
    const int w    = tid >> 6;
    const int lane = tid & 63;
    const int lidx = lane & 15;
    const int quad = lane >> 4;
    const int i0    = blockIdx.x * 64;
    const int kbase = blockIdx.y * (NN / 4);

    float4x acc[4][4];
    #pragma unroll
    for (int a = 0; a < 4; ++a)
        #pragma unroll
        for (int b = 0; b < 4; ++b)
            acc[a][b] = (float4x){0.f, 0.f, 0.f, 0.f};

    for (int ks = 0; ks < 32; ++ks) {
        const int kt = kbase + ks * 32;
        __syncthreads();
        #pragma unroll
        for (int it = 0; it < 2; ++it) {
            int v = tid + it * 256;
            int r = v >> 3, kq = v & 7;
            *(ushort4*)&lds_a[r * 40 + kq * 4] =
                *(const ushort4*)&attn[(size_t)(i0 + r) * NN + kt + kq * 4];
        }
        #pragma unroll
        for (int it = 0; it < 8; ++it) {
            int v = tid + it * 256;
            int n = v >> 3, kq = v & 7;
            *(ushort4*)&lds_h[n * 40 + kq * 4] =
                *(const ushort4*)&hT[(size_t)n * NN + kt + kq * 4];
        }
        __syncthreads();
        short8x af[4], bfr[4];
        #pragma unroll
        for (int t = 0; t < 4; ++t) {
            af[t]  = *(const short8x*)&lds_a[(t * 16 + lidx) * 40 + quad * 8];
            bfr[t] = *(const short8x*)&lds_h[(w * 64 + t * 16 + lidx) * 40 + quad * 8];
        }
        #pragma unroll
        for (int it = 0; it < 4; ++it)
            #pragma unroll
            for (int nt = 0; nt < 4; ++nt)
                acc[it][nt] = __builtin_amdgcn_mfma_f32_16x16x32_bf16(
                    af[it], bfr[nt], acc[it][nt], 0, 0, 0);
    }
    float* pbase = partials + (size_t)blockIdx.y * NN * OUTF;
    #pragma unroll
    for (int it = 0; it < 4; ++it)
        #pragma unroll
        for (int nt = 0; nt < 4; ++nt)
            #pragma unroll
            for (int r = 0; r < 4; ++r) {
                int row = i0 + it * 16 + quad * 4 + r;
                int col = w * 64 + nt * 16 + lidx;
                pbase[(size_t)row * OUTF + col] = acc[it][nt][r];
            }
}

// ============================================================
// K5: out = sum_s partials[s] + bias
// ============================================================
__global__ __launch_bounds__(256) void k_reduce_out(const float* __restrict__ partials,
                                                    const float* __restrict__ bias,
                                                    float* __restrict__ out) {
    const int i = blockIdx.x;
    const int n = threadIdx.x;
    float acc = bias[n];
    #pragma unroll
    for (int s = 0; s < 4; ++s)
        acc += partials[((size_t)s * NN + i) * OUTF + n];
    out[(size_t)i * OUTF + n] = acc;
}

// ============================================================
extern "C" void kernel_launch(void* const* d_in, const int* in_sizes, int n_in,
                              void* d_out, int out_size, void* d_ws, size_t ws_size,
                              hipStream_t stream) {
    const float* feat = (const float*)d_in[0];   // [4096,512]
    const float* adj  = (const float*)d_in[1];   // [4096,4096]
    const float* W    = (const float*)d_in[2];   // [256,512]
    const float* a    = (const float*)d_in[3];   // [4,128]
    const float* bias = (const float*)d_in[4];   // [256]
    float* out = (float*)d_out;                  // [4096,256] fp32

    // workspace layout (50.5 MiB total; featb/Wb/h32 are dead before attn
    // overwrites their region)
    char* ws = (char*)d_ws;
    float*          es    = (float*)(ws + 0);                 // 64 KiB
    float*          ed    = (float*)(ws + (64u << 10));
    float*          Btab  = (float*)(ws + (128u << 10));
    float*          Dtab  = (float*)(ws + (192u << 10));
    unsigned short* hT    = (unsigned short*)(ws + (256u << 10));          // 2 MiB
    unsigned short* attn  = (unsigned short*)(ws + (2560u << 10));         // 32 MiB @2.5M
    unsigned short* featb = (unsigned short*)(ws + (2560u << 10));         // 4 MiB (inside attn region)
    unsigned short* Wb    = (unsigned short*)(ws + (6656u << 10));         // 256 KiB
    float*          h32   = (float*)(ws + (7168u << 10));                  // 4 MiB
    float*          partials = (float*)(ws + (35328u << 10));              // 16 MiB @34.5M

    k_cast      <<<2176,        256, 0, stream>>>(feat, W, featb, Wb);
    k_h_gemm    <<<64,          256, 0, stream>>>(featb, Wb, h32, hT);
    k_edge_proj <<<NN,          256, 0, stream>>>(h32, a, es, ed, Btab, Dtab);
    k_attn      <<<NN,          256, 0, stream>>>(adj, es, ed, Btab, Dtab, attn);
    k_out_gemm  <<<dim3(64, 4), 256, 0, stream>>>(attn, hT, partials);
    k_reduce_out<<<NN,          256, 0, stream>>>(partials, bias, out);
}

// Round 4
// 244.704 us; speedup vs baseline: 1.4377x; 1.3447x over previous
//
#include <hip/hip_runtime.h>
#include <math.h>

// ---- problem constants ----
#define NN      4096   // nodes
#define INF_    512    // in features
#define OUTF    256    // out features
#define NHEAD   4
#define HDIM    64

typedef __attribute__((ext_vector_type(8))) short  short8x;
typedef __attribute__((ext_vector_type(4))) float  float4x;

__device__ __forceinline__ unsigned short f2bf(float x) {
    union { float f; unsigned int u; } c; c.f = x;
    unsigned int r = (c.u + 0x7FFFu + ((c.u >> 16) & 1u)) >> 16;
    return (unsigned short)r;
}
__device__ __forceinline__ float bflo(unsigned int u) {
    union { unsigned int x; float f; } c; c.x = u << 16; return c.f;
}
__device__ __forceinline__ float bfhi(unsigned int u) {
    union { unsigned int x; float f; } c; c.x = u & 0xFFFF0000u; return c.f;
}

// ============================================================
// K0: cast feat and W to bf16
// ============================================================
__global__ __launch_bounds__(256) void k_cast(const float* __restrict__ feat,
                                              const float* __restrict__ W,
                                              unsigned short* __restrict__ featb,
                                              unsigned short* __restrict__ Wb) {
    const int b = blockIdx.x;
    const float* src;
    unsigned short* dst;
    int idx;
    if (b < 2048) { src = feat; dst = featb; idx = b * 1024 + threadIdx.x * 4; }
    else          { src = W;    dst = Wb;    idx = (b - 2048) * 1024 + threadIdx.x * 4; }
    float4x v = *(const float4x*)(src + idx);
    ushort4 u;
    u.x = f2bf(v[0]); u.y = f2bf(v[1]); u.z = f2bf(v[2]); u.w = f2bf(v[3]);
    *(ushort4*)(dst + idx) = u;
}

// ============================================================
// K1: h = feat @ W^T via bf16 MFMA 16x16x32
// ============================================================
__global__ __launch_bounds__(256) void k_h_gemm(const unsigned short* __restrict__ featb,
                                                const unsigned short* __restrict__ Wb,
                                                float* __restrict__ h32,
                                                unsigned short* __restrict__ hT) {
    __shared__ __align__(16) unsigned short lds_f[64 * 40];
    __shared__ __align__(16) unsigned short lds_w[256 * 40];
    const int tid  = threadIdx.x;
    const int w    = tid >> 6;
    const int lane = tid & 63;
    const int lidx = lane & 15;
    const int quad = lane >> 4;
    const int i0   = blockIdx.x * 64;
    const int sr = tid >> 2;
    const int skq = (tid & 3) * 8;

    float4x acc[4][4];
    #pragma unroll
    for (int a = 0; a < 4; ++a)
        #pragma unroll
        for (int b = 0; b < 4; ++b)
            acc[a][b] = (float4x){0.f, 0.f, 0.f, 0.f};

    for (int kt = 0; kt < INF_; kt += 32) {
        __syncthreads();
        *(ushort4*)&lds_f[sr * 40 + skq]     = *(const ushort4*)&featb[(size_t)(i0 + sr) * INF_ + kt + skq];
        *(ushort4*)&lds_f[sr * 40 + skq + 4] = *(const ushort4*)&featb[(size_t)(i0 + sr) * INF_ + kt + skq + 4];
        #pragma unroll
        for (int itr = 0; itr < 4; ++itr) {
            int n = itr * 64 + sr;
            *(ushort4*)&lds_w[n * 40 + skq]     = *(const ushort4*)&Wb[(size_t)n * INF_ + kt + skq];
            *(ushort4*)&lds_w[n * 40 + skq + 4] = *(const ushort4*)&Wb[(size_t)n * INF_ + kt + skq + 4];
        }
        __syncthreads();
        short8x af[4], bw[4];
        #pragma unroll
        for (int t = 0; t < 4; ++t) {
            af[t] = *(const short8x*)&lds_f[(t * 16 + lidx) * 40 + quad * 8];
            bw[t] = *(const short8x*)&lds_w[(w * 64 + t * 16 + lidx) * 40 + quad * 8];
        }
        #pragma unroll
        for (int it = 0; it < 4; ++it)
            #pragma unroll
            for (int nt = 0; nt < 4; ++nt)
                acc[it][nt] = __builtin_amdgcn_mfma_f32_16x16x32_bf16(
                    af[it], bw[nt], acc[it][nt], 0, 0, 0);
    }
    #pragma unroll
    for (int it = 0; it < 4; ++it)
        #pragma unroll
        for (int nt = 0; nt < 4; ++nt) {
            int col = w * 64 + nt * 16 + lidx;
            int m0r = i0 + it * 16 + quad * 4;
            #pragma unroll
            for (int r = 0; r < 4; ++r)
                h32[(size_t)(m0r + r) * OUTF + col] = acc[it][nt][r];
            ushort4 u;
            u.x = f2bf(acc[it][nt][0]); u.y = f2bf(acc[it][nt][1]);
            u.z = f2bf(acc[it][nt][2]); u.w = f2bf(acc[it][nt][3]);
            *(ushort4*)&hT[(size_t)col * NN + m0r] = u;
        }
}

// ============================================================
// K1b: es projections + bf16 tables Bt=exp(ed), Dt=exp(0.2 ed)
// ============================================================
__global__ __launch_bounds__(256) void k_edge_proj(const float* __restrict__ h32,
                                                   const float* __restrict__ a,
                                                   float* __restrict__ es,
                                                   unsigned short* __restrict__ Bt,
                                                   unsigned short* __restrict__ Dt) {
    const int n = blockIdx.x;
    const int w = threadIdx.x >> 6;
    const int lane = threadIdx.x & 63;
    float v  = h32[(size_t)n * OUTF + w * HDIM + lane];
    float s1 = v * a[w * 2 * HDIM + lane];
    float s2 = v * a[w * 2 * HDIM + HDIM + lane];
    #pragma unroll
    for (int off = 32; off; off >>= 1) {
        s1 += __shfl_down(s1, off);
        s2 += __shfl_down(s2, off);
    }
    if (lane == 0) {
        es[n * NHEAD + w] = s1;
        Bt[n * NHEAD + w] = f2bf(__expf(s2));
        Dt[n * NHEAD + w] = f2bf(__expf(0.2f * s2));
    }
}

// ============================================================
// K2 v2: LDS-staged, branch-free attn computation.
// 512 blocks x 256 thr; block = 8 rows, all j. Tables staged in
// LDS per 2048-j tile (bf16, b64 reads, 2-way = free). adj read
// once (P1); mask bits kept in LDS for P2. All selects predicated.
// pos test: B[j] >= exp(-es_i)  (monotonicity of exp)
// ============================================================
__global__ __launch_bounds__(256) void k_attn(const float* __restrict__ adj,
                                              const float* __restrict__ es,
                                              const unsigned short* __restrict__ Bt,
                                              const unsigned short* __restrict__ Dt,
                                              unsigned short* __restrict__ attn) {
    __shared__ __align__(16) unsigned short lB[2048 * 4];   // 16 KB
    __shared__ __align__(16) unsigned short lD[2048 * 4];   // 16 KB
    __shared__ unsigned int lM[8][128];                     // 4 KB mask bits
    const int tid  = threadIdx.x;
    const int wv   = tid >> 6;         // wave 0..3
    const int lane = tid & 63;
    const int r    = tid >> 5;         // row 0..7 (2 per wave)
    const int jl   = tid & 31;         // j lane within row group
    const int i    = blockIdx.x * 8 + r;

    const float4x esv = ((const float4x*)es)[i];
    float TB[4], Ae[4], Ce[4];
    #pragma unroll
    for (int h = 0; h < 4; ++h) {
        TB[h] = __expf(-esv[h]);
        Ae[h] = __expf(esv[h]);
        Ce[h] = __expf(0.2f * esv[h]);
    }
    const float* arow = adj + (size_t)i * NN;

    float S1[4] = {0.f, 0.f, 0.f, 0.f};
    float S2[4] = {0.f, 0.f, 0.f, 0.f};
    float cA[4], cC[4];

    for (int pass = 0; pass < 2; ++pass) {
        for (int t = 0; t < 2; ++t) {
            __syncthreads();
            // stage 2048-j tile of Bt/Dt (dense uint4 copies)
            {
                const uint4* gB = (const uint4*)Bt + t * 1024;
                const uint4* gD = (const uint4*)Dt + t * 1024;
                #pragma unroll
                for (int c = 0; c < 4; ++c) {
                    int idx = c * 256 + tid;
                    ((uint4*)lB)[idx] = gB[idx];
                    ((uint4*)lD)[idx] = gD[idx];
                }
            }
            __syncthreads();
            if (pass == 0) {
                // ---- P1: mask capture + masked table sums ----
                #pragma unroll 4
                for (int jj = 0; jj < 64; ++jj) {
                    int j = jj * 32 + jl;
                    float av = arow[t * 2048 + j];
                    bool am = av > 0.1f;
                    unsigned long long bal = __ballot(am);
                    if (lane == 0)  lM[2 * wv][t * 64 + jj]     = (unsigned int)bal;
                    if (lane == 32) lM[2 * wv + 1][t * 64 + jj] = (unsigned int)(bal >> 32);
                    uint2 bu = *(const uint2*)&lB[j * 4];
                    uint2 du = *(const uint2*)&lD[j * 4];
                    unsigned int mk = am ? 0xFFFFFFFFu : 0u;
                    bu.x &= mk; bu.y &= mk; du.x &= mk; du.y &= mk;
                    float b0 = bflo(bu.x), b1 = bfhi(bu.x), b2 = bflo(bu.y), b3 = bfhi(bu.y);
                    float d0 = bflo(du.x), d1 = bfhi(du.x), d2 = bflo(du.y), d3 = bfhi(du.y);
                    bool p0 = b0 >= TB[0], p1 = b1 >= TB[1], p2 = b2 >= TB[2], p3 = b3 >= TB[3];
                    S1[0] += p0 ? b0 : 0.f;  S2[0] += p0 ? 0.f : d0;
                    S1[1] += p1 ? b1 : 0.f;  S2[1] += p1 ? 0.f : d1;
                    S1[2] += p2 ? b2 : 0.f;  S2[2] += p2 ? 0.f : d2;
                    S1[3] += p3 ? b3 : 0.f;  S2[3] += p3 ? 0.f : d3;
                }
            } else {
                // ---- P2: write bf16 attn row ----
                unsigned short* orow = attn + (size_t)i * NN + t * 2048;
                #pragma unroll 4
                for (int jj = 0; jj < 64; ++jj) {
                    int j = jj * 32 + jl;
                    unsigned int m = lM[r][t * 64 + jj];
                    unsigned int mk = ((m >> jl) & 1u) ? 0xFFFFFFFFu : 0u;
                    uint2 bu = *(const uint2*)&lB[j * 4];
                    uint2 du = *(const uint2*)&lD[j * 4];
                    bu.x &= mk; bu.y &= mk; du.x &= mk; du.y &= mk;
                    float b0 = bflo(bu.x), b1 = bfhi(bu.x), b2 = bflo(bu.y), b3 = bfhi(bu.y);
                    float d0 = bflo(du.x), d1 = bfhi(du.x), d2 = bflo(du.y), d3 = bfhi(du.y);
                    bool p0 = b0 >= TB[0], p1 = b1 >= TB[1], p2 = b2 >= TB[2], p3 = b3 >= TB[3];
                    float p;
                    p  = (p0 ? b0 : d0) * (p0 ? cA[0] : cC[0]);
                    p += (p1 ? b1 : d1) * (p1 ? cA[1] : cC[1]);
                    p += (p2 ? b2 : d2) * (p2 ? cA[2] : cC[2]);
                    p += (p3 ? b3 : d3) * (p3 ? cA[3] : cC[3]);
                    orow[j] = f2bf(p);
                }
            }
        }
        if (pass == 0) {
            // butterfly reduce over the 32-lane row group
            #pragma unroll
            for (int off = 1; off < 32; off <<= 1) {
                #pragma unroll
                for (int h = 0; h < 4; ++h) {
                    S1[h] += __shfl_xor(S1[h], off);
                    S2[h] += __shfl_xor(S2[h], off);
                }
            }
            #pragma unroll
            for (int h = 0; h < 4; ++h) {
                float den = Ae[h] * S1[h] + Ce[h] * S2[h];
                float sc = den > 0.f ? 0.25f / den : 0.f;
                cA[h] = Ae[h] * sc;
                cC[h] = Ce[h] * sc;
            }
        }
    }
}

// ============================================================
// K4: partials[s] = attn[:, ks] @ h[ks, :]  (bf16 MFMA 16x16x32)
// ============================================================
__global__ __launch_bounds__(256) void k_out_gemm(const unsigned short* __restrict__ attn,
                                                  const unsigned short* __restrict__ hT,
                                                  float* __restrict__ partials) {
    __shared__ __align__(16) unsigned short lds_a[64 * 40];
    __shared__ __align__(16) unsigned short lds_h[256 * 40];
    const int tid  = threadIdx.x;
    const int w    = tid >> 6;
    const int lane = tid & 63;
    const int lidx = lane & 15;
    const int quad = lane >> 4;
    const int i0    = blockIdx.x * 64;
    const int kbase = blockIdx.y * (NN / 4);

    float4x acc[4][4];
    #pragma unroll
    for (int a = 0; a < 4; ++a)
        #pragma unroll
        for (int b = 0; b < 4; ++b)
            acc[a][b] = (float4x){0.f, 0.f, 0.f, 0.f};

    for (int ks = 0; ks < 32; ++ks) {
        const int kt = kbase + ks * 32;
        __syncthreads();
        #pragma unroll
        for (int it = 0; it < 2; ++it) {
            int v = tid + it * 256;
            int rr = v >> 3, kq = v & 7;
            *(ushort4*)&lds_a[rr * 40 + kq * 4] =
                *(const ushort4*)&attn[(size_t)(i0 + rr) * NN + kt + kq * 4];
        }
        #pragma unroll
        for (int it = 0; it < 8; ++it) {
            int v = tid + it * 256;
            int n = v >> 3, kq = v & 7;
            *(ushort4*)&lds_h[n * 40 + kq * 4] =
                *(const ushort4*)&hT[(size_t)n * NN + kt + kq * 4];
        }
        __syncthreads();
        short8x af[4], bfr[4];
        #pragma unroll
        for (int t = 0; t < 4; ++t) {
            af[t]  = *(const short8x*)&lds_a[(t * 16 + lidx) * 40 + quad * 8];
            bfr[t] = *(const short8x*)&lds_h[(w * 64 + t * 16 + lidx) * 40 + quad * 8];
        }
        #pragma unroll
        for (int it = 0; it < 4; ++it)
            #pragma unroll
            for (int nt = 0; nt < 4; ++nt)
                acc[it][nt] = __builtin_amdgcn_mfma_f32_16x16x32_bf16(
                    af[it], bfr[nt], acc[it][nt], 0, 0, 0);
    }
    float* pbase = partials + (size_t)blockIdx.y * NN * OUTF;
    #pragma unroll
    for (int it = 0; it < 4; ++it)
        #pragma unroll
        for (int nt = 0; nt < 4; ++nt)
            #pragma unroll
            for (int rr = 0; rr < 4; ++rr) {
                int row = i0 + it * 16 + quad * 4 + rr;
                int col = w * 64 + nt * 16 + lidx;
                pbase[(size_t)row * OUTF + col] = acc[it][nt][rr];
            }
}

// ============================================================
// K5: out = sum_s partials[s] + bias
// ============================================================
__global__ __launch_bounds__(256) void k_reduce_out(const float* __restrict__ partials,
                                                    const float* __restrict__ bias,
                                                    float* __restrict__ out) {
    const int i = blockIdx.x;
    const int n = threadIdx.x;
    float acc = bias[n];
    #pragma unroll
    for (int s = 0; s < 4; ++s)
        acc += partials[((size_t)s * NN + i) * OUTF + n];
    out[(size_t)i * OUTF + n] = acc;
}

// ============================================================
extern "C" void kernel_launch(void* const* d_in, const int* in_sizes, int n_in,
                              void* d_out, int out_size, void* d_ws, size_t ws_size,
                              hipStream_t stream) {
    const float* feat = (const float*)d_in[0];   // [4096,512]
    const float* adj  = (const float*)d_in[1];   // [4096,4096]
    const float* W    = (const float*)d_in[2];   // [256,512]
    const float* a    = (const float*)d_in[3];   // [4,128]
    const float* bias = (const float*)d_in[4];   // [256]
    float* out = (float*)d_out;                  // [4096,256] fp32

    // workspace layout (~50.3 MiB; featb/Wb/h32 are dead before attn
    // overwrites their region)
    char* ws = (char*)d_ws;
    float*          es    = (float*)(ws + 0);                        // 64 KiB
    unsigned short* Btb   = (unsigned short*)(ws + (64u << 10));     // 32 KiB
    unsigned short* Dtb   = (unsigned short*)(ws + (96u << 10));     // 32 KiB
    unsigned short* hT    = (unsigned short*)(ws + (256u << 10));    // 2 MiB
    unsigned short* attn  = (unsigned short*)(ws + (2560u << 10));   // 32 MiB
    unsigned short* featb = (unsigned short*)(ws + (2560u << 10));   // 4 MiB (inside attn region)
    unsigned short* Wb    = (unsigned short*)(ws + (6656u << 10));   // 256 KiB
    float*          h32   = (float*)(ws + (7168u << 10));            // 4 MiB (inside attn region)
    float*          partials = (float*)(ws + (35328u << 10));        // 16 MiB

    k_cast      <<<2176,        256, 0, stream>>>(feat, W, featb, Wb);
    k_h_gemm    <<<64,          256, 0, stream>>>(featb, Wb, h32, hT);
    k_edge_proj <<<NN,          256, 0, stream>>>(h32, a, es, Btb, Dtb);
    k_attn      <<<512,         256, 0, stream>>>(adj, es, Btb, Dtb, attn);
    k_out_gemm  <<<dim3(64, 4), 256, 0, stream>>>(attn, hT, partials);
    k_reduce_out<<<NN,          256, 0, stream>>>(partials, bias, out);
}

// Round 5
// 190.003 us; speedup vs baseline: 1.8516x; 1.2879x over previous
//
#include <hip/hip_runtime.h>
#include <math.h>

// ---- problem constants ----
#define NN      4096   // nodes
#define INF_    512    // in features
#define OUTF    256    // out features
#define NHEAD   4
#define HDIM    64

typedef __attribute__((ext_vector_type(8))) short  short8x;
typedef __attribute__((ext_vector_type(4))) float  float4x;

__device__ __forceinline__ unsigned short f2bf(float x) {
    union { float f; unsigned int u; } c; c.f = x;
    unsigned int r = (c.u + 0x7FFFu + ((c.u >> 16) & 1u)) >> 16;
    return (unsigned short)r;
}
__device__ __forceinline__ float bflo(unsigned int u) {
    union { unsigned int x; float f; } c; c.x = u << 16; return c.f;
}
__device__ __forceinline__ float bfhi(unsigned int u) {
    union { unsigned int x; float f; } c; c.x = u & 0xFFFF0000u; return c.f;
}

// ============================================================
// K0: cast feat and W to bf16
// ============================================================
__global__ __launch_bounds__(256) void k_cast(const float* __restrict__ feat,
                                              const float* __restrict__ W,
                                              unsigned short* __restrict__ featb,
                                              unsigned short* __restrict__ Wb) {
    const int b = blockIdx.x;
    const float* src;
    unsigned short* dst;
    int idx;
    if (b < 2048) { src = feat; dst = featb; idx = b * 1024 + threadIdx.x * 4; }
    else          { src = W;    dst = Wb;    idx = (b - 2048) * 1024 + threadIdx.x * 4; }
    float4x v = *(const float4x*)(src + idx);
    ushort4 u;
    u.x = f2bf(v[0]); u.y = f2bf(v[1]); u.z = f2bf(v[2]); u.w = f2bf(v[3]);
    *(ushort4*)(dst + idx) = u;
}

// ============================================================
// K1: h = feat @ W^T via bf16 MFMA 16x16x32
// grid (4 o-tiles, 64 i-tiles); block tile 64i x 64o; reg prefetch
// ============================================================
__global__ __launch_bounds__(256) void k_h_gemm(const unsigned short* __restrict__ featb,
                                                const unsigned short* __restrict__ Wb,
                                                float* __restrict__ h32,
                                                unsigned short* __restrict__ hT) {
    __shared__ __align__(16) unsigned short lds_f[64 * 40];
    __shared__ __align__(16) unsigned short lds_w[64 * 40];
    const int tid  = threadIdx.x;
    const int w    = tid >> 6;
    const int lane = tid & 63;
    const int lidx = lane & 15;
    const int quad = lane >> 4;
    const int o0 = blockIdx.x * 64;
    const int i0 = blockIdx.y * 64;
    const int sr = tid >> 2;
    const int skq = (tid & 3) * 8;

    float4x acc[4];
    #pragma unroll
    for (int nt = 0; nt < 4; ++nt) acc[nt] = (float4x){0.f, 0.f, 0.f, 0.f};

    ushort4 pf0, pf1, pw0, pw1;
    {
        pf0 = *(const ushort4*)&featb[(size_t)(i0 + sr) * INF_ + skq];
        pf1 = *(const ushort4*)&featb[(size_t)(i0 + sr) * INF_ + skq + 4];
        pw0 = *(const ushort4*)&Wb[(size_t)(o0 + sr) * INF_ + skq];
        pw1 = *(const ushort4*)&Wb[(size_t)(o0 + sr) * INF_ + skq + 4];
    }
    for (int kt = 0; kt < INF_; kt += 32) {
        __syncthreads();
        *(ushort4*)&lds_f[sr * 40 + skq]     = pf0;
        *(ushort4*)&lds_f[sr * 40 + skq + 4] = pf1;
        *(ushort4*)&lds_w[sr * 40 + skq]     = pw0;
        *(ushort4*)&lds_w[sr * 40 + skq + 4] = pw1;
        __syncthreads();
        if (kt + 32 < INF_) {
            int kn = kt + 32;
            pf0 = *(const ushort4*)&featb[(size_t)(i0 + sr) * INF_ + kn + skq];
            pf1 = *(const ushort4*)&featb[(size_t)(i0 + sr) * INF_ + kn + skq + 4];
            pw0 = *(const ushort4*)&Wb[(size_t)(o0 + sr) * INF_ + kn + skq];
            pw1 = *(const ushort4*)&Wb[(size_t)(o0 + sr) * INF_ + kn + skq + 4];
        }
        short8x af = *(const short8x*)&lds_f[(w * 16 + lidx) * 40 + quad * 8];
        short8x bw[4];
        #pragma unroll
        for (int t = 0; t < 4; ++t)
            bw[t] = *(const short8x*)&lds_w[(t * 16 + lidx) * 40 + quad * 8];
        #pragma unroll
        for (int nt = 0; nt < 4; ++nt)
            acc[nt] = __builtin_amdgcn_mfma_f32_16x16x32_bf16(af, bw[nt], acc[nt], 0, 0, 0);
    }
    #pragma unroll
    for (int nt = 0; nt < 4; ++nt) {
        int col = o0 + nt * 16 + lidx;
        int m0r = i0 + w * 16 + quad * 4;
        #pragma unroll
        for (int rr = 0; rr < 4; ++rr)
            h32[(size_t)(m0r + rr) * OUTF + col] = acc[nt][rr];
        ushort4 u;
        u.x = f2bf(acc[nt][0]); u.y = f2bf(acc[nt][1]);
        u.z = f2bf(acc[nt][2]); u.w = f2bf(acc[nt][3]);
        *(ushort4*)&hT[(size_t)col * NN + m0r] = u;
    }
}

// ============================================================
// K1b: es projections + bf16 tables Bt=exp(ed), Dt=exp(0.2 ed)
// ============================================================
__global__ __launch_bounds__(256) void k_edge_proj(const float* __restrict__ h32,
                                                   const float* __restrict__ a,
                                                   float* __restrict__ es,
                                                   unsigned short* __restrict__ Bt,
                                                   unsigned short* __restrict__ Dt) {
    const int n = blockIdx.x;
    const int w = threadIdx.x >> 6;
    const int lane = threadIdx.x & 63;
    float v  = h32[(size_t)n * OUTF + w * HDIM + lane];
    float s1 = v * a[w * 2 * HDIM + lane];
    float s2 = v * a[w * 2 * HDIM + HDIM + lane];
    #pragma unroll
    for (int off = 32; off; off >>= 1) {
        s1 += __shfl_down(s1, off);
        s2 += __shfl_down(s2, off);
    }
    if (lane == 0) {
        es[n * NHEAD + w] = s1;
        Bt[n * NHEAD + w] = f2bf(__expf(s2));
        Dt[n * NHEAD + w] = f2bf(__expf(0.2f * s2));
    }
}

// ============================================================
// K2a: per-row per-head denominators -> coefA/coefC
// grid 2048 x 256; 2 rows/block, 128 lanes/row, 4 j per lane-iter.
// No LDS staging: dense uint4 table loads (L2-resident), predicated.
// pos test: B[j] >= exp(-es_i)  (monotonicity of exp)
// ============================================================
__global__ __launch_bounds__(256) void k_den(const float* __restrict__ adj,
                                             const float* __restrict__ es,
                                             const unsigned short* __restrict__ Bt,
                                             const unsigned short* __restrict__ Dt,
                                             float* __restrict__ coefA,
                                             float* __restrict__ coefC) {
    __shared__ float red[2][2][8];
    const int tid = threadIdx.x;
    const int r  = tid >> 7;          // row in block
    const int l  = tid & 127;         // lane in row-group
    const int wv = (tid >> 6) & 1;    // wave within row-group
    const int i  = blockIdx.x * 2 + r;

    const float4x esv = ((const float4x*)es)[i];
    float TB[4];
    #pragma unroll
    for (int h = 0; h < 4; ++h) TB[h] = __expf(-esv[h]);
    const float4x* arow4 = (const float4x*)(adj + (size_t)i * NN);
    const uint4* B4 = (const uint4*)Bt;
    const uint4* D4 = (const uint4*)Dt;

    float S1[4] = {0.f, 0.f, 0.f, 0.f};
    float S2[4] = {0.f, 0.f, 0.f, 0.f};
    #pragma unroll
    for (int it = 0; it < 8; ++it) {
        int jv = it * 128 + l;        // covers j = jv*4 .. jv*4+3
        float4x av = arow4[jv];
        uint4 bu0 = B4[jv * 2], bu1 = B4[jv * 2 + 1];
        uint4 du0 = D4[jv * 2], du1 = D4[jv * 2 + 1];
        const unsigned int* bw = (const unsigned int*)&bu0;  // 8 words: j0..j3
        const unsigned int* dw = (const unsigned int*)&du0;
        (void)bu1; (void)du1;  // contiguous in memory layout below
        unsigned int bwv[8] = {bu0.x, bu0.y, bu0.z, bu0.w, bu1.x, bu1.y, bu1.z, bu1.w};
        unsigned int dwv[8] = {du0.x, du0.y, du0.z, du0.w, du1.x, du1.y, du1.z, du1.w};
        (void)bw; (void)dw;
        #pragma unroll
        for (int u = 0; u < 4; ++u) {
            bool m = av[u] > 0.1f;
            float b0 = bflo(bwv[u * 2]), b1 = bfhi(bwv[u * 2]);
            float b2 = bflo(bwv[u * 2 + 1]), b3 = bfhi(bwv[u * 2 + 1]);
            float d0 = bflo(dwv[u * 2]), d1 = bfhi(dwv[u * 2]);
            float d2 = bflo(dwv[u * 2 + 1]), d3 = bfhi(dwv[u * 2 + 1]);
            bool p0 = b0 >= TB[0], p1 = b1 >= TB[1], p2 = b2 >= TB[2], p3 = b3 >= TB[3];
            S1[0] += (m && p0) ? b0 : 0.f;   S2[0] += (m && !p0) ? d0 : 0.f;
            S1[1] += (m && p1) ? b1 : 0.f;   S2[1] += (m && !p1) ? d1 : 0.f;
            S1[2] += (m && p2) ? b2 : 0.f;   S2[2] += (m && !p2) ? d2 : 0.f;
            S1[3] += (m && p3) ? b3 : 0.f;   S2[3] += (m && !p3) ? d3 : 0.f;
        }
    }
    // wave butterfly (64 lanes)
    #pragma unroll
    for (int off = 1; off < 64; off <<= 1) {
        #pragma unroll
        for (int h = 0; h < 4; ++h) {
            S1[h] += __shfl_xor(S1[h], off);
            S2[h] += __shfl_xor(S2[h], off);
        }
    }
    if ((tid & 63) == 0) {
        #pragma unroll
        for (int h = 0; h < 4; ++h) { red[r][wv][h] = S1[h]; red[r][wv][4 + h] = S2[h]; }
    }
    __syncthreads();
    if (tid < 8) {
        int rr = tid >> 2, h = tid & 3;
        int ii = blockIdx.x * 2 + rr;
        float s1 = red[rr][0][h] + red[rr][1][h];
        float s2 = red[rr][0][4 + h] + red[rr][1][4 + h];
        float e = es[ii * NHEAD + h];
        float A = __expf(e), C = __expf(0.2f * e);
        float den = A * s1 + C * s2;
        float sc = den > 0.f ? 0.25f / den : 0.f;
        coefA[ii * NHEAD + h] = A * sc;
        coefC[ii * NHEAD + h] = C * sc;
    }
}

// ============================================================
// K2b: write bf16 attn rows from coefs (pure stream, no LDS)
// ============================================================
__global__ __launch_bounds__(256) void k_write(const float* __restrict__ adj,
                                               const float* __restrict__ es,
                                               const unsigned short* __restrict__ Bt,
                                               const unsigned short* __restrict__ Dt,
                                               const float* __restrict__ coefA,
                                               const float* __restrict__ coefC,
                                               unsigned short* __restrict__ attn) {
    const int tid = threadIdx.x;
    const int r = tid >> 7;
    const int l = tid & 127;
    const int i = blockIdx.x * 2 + r;

    const float4x esv = ((const float4x*)es)[i];
    const float4x cA = ((const float4x*)coefA)[i];
    const float4x cC = ((const float4x*)coefC)[i];
    float TB[4];
    #pragma unroll
    for (int h = 0; h < 4; ++h) TB[h] = __expf(-esv[h]);
    const float4x* arow4 = (const float4x*)(adj + (size_t)i * NN);
    const uint4* B4 = (const uint4*)Bt;
    const uint4* D4 = (const uint4*)Dt;
    unsigned short* orow = attn + (size_t)i * NN;

    #pragma unroll
    for (int it = 0; it < 8; ++it) {
        int jv = it * 128 + l;
        float4x av = arow4[jv];
        uint4 bu0 = B4[jv * 2], bu1 = B4[jv * 2 + 1];
        uint4 du0 = D4[jv * 2], du1 = D4[jv * 2 + 1];
        unsigned int bwv[8] = {bu0.x, bu0.y, bu0.z, bu0.w, bu1.x, bu1.y, bu1.z, bu1.w};
        unsigned int dwv[8] = {du0.x, du0.y, du0.z, du0.w, du1.x, du1.y, du1.z, du1.w};
        ushort4 o;
        unsigned short* op = (unsigned short*)&o;
        #pragma unroll
        for (int u = 0; u < 4; ++u) {
            float b0 = bflo(bwv[u * 2]), b1 = bfhi(bwv[u * 2]);
            float b2 = bflo(bwv[u * 2 + 1]), b3 = bfhi(bwv[u * 2 + 1]);
            float d0 = bflo(dwv[u * 2]), d1 = bfhi(dwv[u * 2]);
            float d2 = bflo(dwv[u * 2 + 1]), d3 = bfhi(dwv[u * 2 + 1]);
            float p;
            p  = (b0 >= TB[0]) ? cA[0] * b0 : cC[0] * d0;
            p += (b1 >= TB[1]) ? cA[1] * b1 : cC[1] * d1;
            p += (b2 >= TB[2]) ? cA[2] * b2 : cC[2] * d2;
            p += (b3 >= TB[3]) ? cA[3] * b3 : cC[3] * d3;
            op[u] = f2bf((av[u] > 0.1f) ? p : 0.f);
        }
        *(ushort4*)&orow[jv * 4] = o;
    }
}

// ============================================================
// K4: partials[s] = attn[:, ks] @ h[ks, :]  (bf16 MFMA, reg prefetch)
// ============================================================
__global__ __launch_bounds__(256) void k_out_gemm(const unsigned short* __restrict__ attn,
                                                  const unsigned short* __restrict__ hT,
                                                  float* __restrict__ partials) {
    __shared__ __align__(16) unsigned short lds_a[64 * 40];
    __shared__ __align__(16) unsigned short lds_h[256 * 40];
    const int tid  = threadIdx.x;
    const int w    = tid >> 6;
    const int lane = tid & 63;
    const int lidx = lane & 15;
    const int quad = lane >> 4;
    const int i0    = blockIdx.x * 64;
    const int kbase = blockIdx.y * (NN / 4);
    const int srow = tid >> 3;      // 0..31
    const int skq  = tid & 7;

    float4x acc[4][4];
    #pragma unroll
    for (int a = 0; a < 4; ++a)
        #pragma unroll
        for (int b = 0; b < 4; ++b)
            acc[a][b] = (float4x){0.f, 0.f, 0.f, 0.f};

    ushort4 pa[2], ph[8];
    #pragma unroll
    for (int it = 0; it < 2; ++it)
        pa[it] = *(const ushort4*)&attn[(size_t)(i0 + it * 32 + srow) * NN + kbase + skq * 4];
    #pragma unroll
    for (int it = 0; it < 8; ++it)
        ph[it] = *(const ushort4*)&hT[(size_t)(it * 32 + srow) * NN + kbase + skq * 4];

    for (int ks = 0; ks < 32; ++ks) {
        __syncthreads();
        #pragma unroll
        for (int it = 0; it < 2; ++it)
            *(ushort4*)&lds_a[(it * 32 + srow) * 40 + skq * 4] = pa[it];
        #pragma unroll
        for (int it = 0; it < 8; ++it)
            *(ushort4*)&lds_h[(it * 32 + srow) * 40 + skq * 4] = ph[it];
        __syncthreads();
        if (ks < 31) {
            const int ktn = kbase + (ks + 1) * 32;
            #pragma unroll
            for (int it = 0; it < 2; ++it)
                pa[it] = *(const ushort4*)&attn[(size_t)(i0 + it * 32 + srow) * NN + ktn + skq * 4];
            #pragma unroll
            for (int it = 0; it < 8; ++it)
                ph[it] = *(const ushort4*)&hT[(size_t)(it * 32 + srow) * NN + ktn + skq * 4];
        }
        short8x af[4], bfr[4];
        #pragma unroll
        for (int t = 0; t < 4; ++t) {
            af[t]  = *(const short8x*)&lds_a[(t * 16 + lidx) * 40 + quad * 8];
            bfr[t] = *(const short8x*)&lds_h[(w * 64 + t * 16 + lidx) * 40 + quad * 8];
        }
        #pragma unroll
        for (int it = 0; it < 4; ++it)
            #pragma unroll
            for (int nt = 0; nt < 4; ++nt)
                acc[it][nt] = __builtin_amdgcn_mfma_f32_16x16x32_bf16(
                    af[it], bfr[nt], acc[it][nt], 0, 0, 0);
    }
    float* pbase = partials + (size_t)blockIdx.y * NN * OUTF;
    #pragma unroll
    for (int it = 0; it < 4; ++it)
        #pragma unroll
        for (int nt = 0; nt < 4; ++nt)
            #pragma unroll
            for (int rr = 0; rr < 4; ++rr) {
                int row = i0 + it * 16 + quad * 4 + rr;
                int col = w * 64 + nt * 16 + lidx;
                pbase[(size_t)row * OUTF + col] = acc[it][nt][rr];
            }
}

// ============================================================
// K5: out = sum_s partials[s] + bias
// ============================================================
__global__ __launch_bounds__(256) void k_reduce_out(const float* __restrict__ partials,
                                                    const float* __restrict__ bias,
                                                    float* __restrict__ out) {
    const int i = blockIdx.x;
    const int n = threadIdx.x;
    float acc = bias[n];
    #pragma unroll
    for (int s = 0; s < 4; ++s)
        acc += partials[((size_t)s * NN + i) * OUTF + n];
    out[(size_t)i * OUTF + n] = acc;
}

// ============================================================
extern "C" void kernel_launch(void* const* d_in, const int* in_sizes, int n_in,
                              void* d_out, int out_size, void* d_ws, size_t ws_size,
                              hipStream_t stream) {
    const float* feat = (const float*)d_in[0];   // [4096,512]
    const float* adj  = (const float*)d_in[1];   // [4096,4096]
    const float* W    = (const float*)d_in[2];   // [256,512]
    const float* a    = (const float*)d_in[3];   // [4,128]
    const float* bias = (const float*)d_in[4];   // [256]
    float* out = (float*)d_out;                  // [4096,256] fp32

    char* ws = (char*)d_ws;
    float*          es    = (float*)(ws + 0);                        // 64 KiB
    unsigned short* Btb   = (unsigned short*)(ws + (64u << 10));     // 32 KiB
    unsigned short* Dtb   = (unsigned short*)(ws + (96u << 10));     // 32 KiB
    float*          coefA = (float*)(ws + (128u << 10));             // 64 KiB
    float*          coefC = (float*)(ws + (192u << 10));             // 64 KiB
    unsigned short* hT    = (unsigned short*)(ws + (256u << 10));    // 2 MiB
    unsigned short* attn  = (unsigned short*)(ws + (2560u << 10));   // 32 MiB
    unsigned short* featb = (unsigned short*)(ws + (2560u << 10));   // 4 MiB (dead before attn written)
    unsigned short* Wb    = (unsigned short*)(ws + (6656u << 10));   // 256 KiB (dead before attn)
    float*          h32   = (float*)(ws + (7168u << 10));            // 4 MiB (dead before attn)
    float*          partials = (float*)(ws + (35328u << 10));        // 16 MiB

    k_cast      <<<2176,        256, 0, stream>>>(feat, W, featb, Wb);
    k_h_gemm    <<<dim3(4, 64), 256, 0, stream>>>(featb, Wb, h32, hT);
    k_edge_proj <<<NN,          256, 0, stream>>>(h32, a, es, Btb, Dtb);
    k_den       <<<2048,        256, 0, stream>>>(adj, es, Btb, Dtb, coefA, coefC);
    k_write     <<<2048,        256, 0, stream>>>(adj, es, Btb, Dtb, coefA, coefC, attn);
    k_out_gemm  <<<dim3(64, 4), 256, 0, stream>>>(attn, hT, partials);
    k_reduce_out<<<NN,          256, 0, stream>>>(partials, bias, out);
}

// Round 6
// 184.013 us; speedup vs baseline: 1.9119x; 1.0326x over previous
//
#include <hip/hip_runtime.h>
#include <math.h>

// ---- problem constants ----
#define NN      4096   // nodes
#define INF_    512    // in features
#define OUTF    256    // out features
#define NHEAD   4
#define HDIM    64
#define KSPLIT  8

typedef __attribute__((ext_vector_type(8))) short  short8x;
typedef __attribute__((ext_vector_type(4))) float  float4x;

__device__ __forceinline__ unsigned short f2bf(float x) {
    union { float f; unsigned int u; } c; c.f = x;
    unsigned int r = (c.u + 0x7FFFu + ((c.u >> 16) & 1u)) >> 16;
    return (unsigned short)r;
}
__device__ __forceinline__ float bflo(unsigned int u) {
    union { unsigned int x; float f; } c; c.x = u << 16; return c.f;
}
__device__ __forceinline__ float bfhi(unsigned int u) {
    union { unsigned int x; float f; } c; c.x = u & 0xFFFF0000u; return c.f;
}

// ============================================================
// K0: blocks 0..7: wsrc/wdst[k][h] = sum_d W[h*64+d][k] * a[h][d(/+64)]
//     blocks 8..2183: cast feat and W to bf16
// ============================================================
__global__ __launch_bounds__(256) void k_prep(const float* __restrict__ feat,
                                              const float* __restrict__ W,
                                              const float* __restrict__ a,
                                              unsigned short* __restrict__ featb,
                                              unsigned short* __restrict__ Wb,
                                              float* __restrict__ wsrc,
                                              float* __restrict__ wdst) {
    const int b = blockIdx.x;
    if (b < 8) {
        const int kk = threadIdx.x & 63, h = threadIdx.x >> 6;
        const int k = b * 64 + kk;
        float s = 0.f, d2 = 0.f;
        #pragma unroll 8
        for (int d = 0; d < 64; ++d) {
            float wv = W[(size_t)(h * HDIM + d) * INF_ + k];
            s  += wv * a[h * 2 * HDIM + d];
            d2 += wv * a[h * 2 * HDIM + HDIM + d];
        }
        wsrc[k * NHEAD + h] = s;
        wdst[k * NHEAD + h] = d2;
        return;
    }
    const int bb = b - 8;
    const float* src;
    unsigned short* dst;
    int idx;
    if (bb < 2048) { src = feat; dst = featb; idx = bb * 1024 + threadIdx.x * 4; }
    else           { src = W;    dst = Wb;    idx = (bb - 2048) * 1024 + threadIdx.x * 4; }
    float4x v = *(const float4x*)(src + idx);
    ushort4 u;
    u.x = f2bf(v[0]); u.y = f2bf(v[1]); u.z = f2bf(v[2]); u.w = f2bf(v[3]);
    *(ushort4*)(dst + idx) = u;
}

// ============================================================
// K1: es = feat @ wsrc, ed = feat @ wdst; emit es + bf16 exp tables.
// grid 256 x 256: 16 rows/block, 16 lanes/row
// ============================================================
__global__ __launch_bounds__(256) void k_edge(const float* __restrict__ feat,
                                              const float* __restrict__ wsrc,
                                              const float* __restrict__ wdst,
                                              float* __restrict__ es,
                                              unsigned short* __restrict__ Bt,
                                              unsigned short* __restrict__ Dt) {
    const int r = blockIdx.x * 16 + (threadIdx.x >> 4);
    const int lane = threadIdx.x & 15;
    float s[4] = {0.f, 0.f, 0.f, 0.f};
    float d[4] = {0.f, 0.f, 0.f, 0.f};
    for (int kk = 0; kk < 32; ++kk) {
        int k = kk * 16 + lane;
        float f = feat[(size_t)r * INF_ + k];
        float4x ws = ((const float4x*)wsrc)[k];
        float4x wd = ((const float4x*)wdst)[k];
        #pragma unroll
        for (int h = 0; h < 4; ++h) { s[h] += f * ws[h]; d[h] += f * wd[h]; }
    }
    #pragma unroll
    for (int off = 1; off < 16; off <<= 1) {
        #pragma unroll
        for (int h = 0; h < 4; ++h) {
            s[h] += __shfl_xor(s[h], off);
            d[h] += __shfl_xor(d[h], off);
        }
    }
    if (lane == 0) {
        #pragma unroll
        for (int h = 0; h < 4; ++h) {
            es[r * NHEAD + h] = s[h];
            Bt[r * NHEAD + h] = f2bf(__expf(d[h]));
            Dt[r * NHEAD + h] = f2bf(__expf(0.2f * d[h]));
        }
    }
}

// ============================================================
// K2: h = feat @ W^T via bf16 MFMA; writes hT bf16 only.
// grid (4 o-tiles, 64 i-tiles); 64x64 tile; reg prefetch
// ============================================================
__global__ __launch_bounds__(256) void k_h_gemm(const unsigned short* __restrict__ featb,
                                                const unsigned short* __restrict__ Wb,
                                                unsigned short* __restrict__ hT) {
    __shared__ __align__(16) unsigned short lds_f[64 * 40];
    __shared__ __align__(16) unsigned short lds_w[64 * 40];
    const int tid  = threadIdx.x;
    const int w    = tid >> 6;
    const int lane = tid & 63;
    const int lidx = lane & 15;
    const int quad = lane >> 4;
    const int o0 = blockIdx.x * 64;
    const int i0 = blockIdx.y * 64;
    const int sr = tid >> 2;
    const int skq = (tid & 3) * 8;

    float4x acc[4];
    #pragma unroll
    for (int nt = 0; nt < 4; ++nt) acc[nt] = (float4x){0.f, 0.f, 0.f, 0.f};

    ushort4 pf0 = *(const ushort4*)&featb[(size_t)(i0 + sr) * INF_ + skq];
    ushort4 pf1 = *(const ushort4*)&featb[(size_t)(i0 + sr) * INF_ + skq + 4];
    ushort4 pw0 = *(const ushort4*)&Wb[(size_t)(o0 + sr) * INF_ + skq];
    ushort4 pw1 = *(const ushort4*)&Wb[(size_t)(o0 + sr) * INF_ + skq + 4];

    for (int kt = 0; kt < INF_; kt += 32) {
        __syncthreads();
        *(ushort4*)&lds_f[sr * 40 + skq]     = pf0;
        *(ushort4*)&lds_f[sr * 40 + skq + 4] = pf1;
        *(ushort4*)&lds_w[sr * 40 + skq]     = pw0;
        *(ushort4*)&lds_w[sr * 40 + skq + 4] = pw1;
        __syncthreads();
        if (kt + 32 < INF_) {
            int kn = kt + 32;
            pf0 = *(const ushort4*)&featb[(size_t)(i0 + sr) * INF_ + kn + skq];
            pf1 = *(const ushort4*)&featb[(size_t)(i0 + sr) * INF_ + kn + skq + 4];
            pw0 = *(const ushort4*)&Wb[(size_t)(o0 + sr) * INF_ + kn + skq];
            pw1 = *(const ushort4*)&Wb[(size_t)(o0 + sr) * INF_ + kn + skq + 4];
        }
        short8x af = *(const short8x*)&lds_f[(w * 16 + lidx) * 40 + quad * 8];
        short8x bw[4];
        #pragma unroll
        for (int t = 0; t < 4; ++t)
            bw[t] = *(const short8x*)&lds_w[(t * 16 + lidx) * 40 + quad * 8];
        #pragma unroll
        for (int nt = 0; nt < 4; ++nt)
            acc[nt] = __builtin_amdgcn_mfma_f32_16x16x32_bf16(af, bw[nt], acc[nt], 0, 0, 0);
    }
    #pragma unroll
    for (int nt = 0; nt < 4; ++nt) {
        int col = o0 + nt * 16 + lidx;
        int m0r = i0 + w * 16 + quad * 4;
        ushort4 u;
        u.x = f2bf(acc[nt][0]); u.y = f2bf(acc[nt][1]);
        u.z = f2bf(acc[nt][2]); u.w = f2bf(acc[nt][3]);
        *(ushort4*)&hT[(size_t)col * NN + m0r] = u;
    }
}

// ============================================================
// K3: fused den + attn-row write. grid 2048 x 256: 2 rows/block,
// 128 lanes/row. No LDS staging; predicated; pos test B[j]>=exp(-es).
// ============================================================
__global__ __launch_bounds__(256) void k_attn(const float* __restrict__ adj,
                                              const float* __restrict__ es,
                                              const unsigned short* __restrict__ Bt,
                                              const unsigned short* __restrict__ Dt,
                                              unsigned short* __restrict__ attn) {
    __shared__ float red[2][2][8];
    __shared__ float cfs[2][8];
    const int tid = threadIdx.x;
    const int r  = tid >> 7;
    const int l  = tid & 127;
    const int wv = (tid >> 6) & 1;
    const int i  = blockIdx.x * 2 + r;

    const float4x esv = ((const float4x*)es)[i];
    float TB[4];
    #pragma unroll
    for (int h = 0; h < 4; ++h) TB[h] = __expf(-esv[h]);
    const float4x* arow4 = (const float4x*)(adj + (size_t)i * NN);
    const uint4* B4 = (const uint4*)Bt;
    const uint4* D4 = (const uint4*)Dt;

    // ---- pass 1: masked sums ----
    float S1[4] = {0.f, 0.f, 0.f, 0.f};
    float S2[4] = {0.f, 0.f, 0.f, 0.f};
    #pragma unroll
    for (int it = 0; it < 8; ++it) {
        int jv = it * 128 + l;
        float4x av = arow4[jv];
        uint4 bu0 = B4[jv * 2], bu1 = B4[jv * 2 + 1];
        uint4 du0 = D4[jv * 2], du1 = D4[jv * 2 + 1];
        unsigned int bwv[8] = {bu0.x, bu0.y, bu0.z, bu0.w, bu1.x, bu1.y, bu1.z, bu1.w};
        unsigned int dwv[8] = {du0.x, du0.y, du0.z, du0.w, du1.x, du1.y, du1.z, du1.w};
        #pragma unroll
        for (int u = 0; u < 4; ++u) {
            bool m = av[u] > 0.1f;
            float b0 = bflo(bwv[u * 2]), b1 = bfhi(bwv[u * 2]);
            float b2 = bflo(bwv[u * 2 + 1]), b3 = bfhi(bwv[u * 2 + 1]);
            float d0 = bflo(dwv[u * 2]), d1 = bfhi(dwv[u * 2]);
            float d2 = bflo(dwv[u * 2 + 1]), d3 = bfhi(dwv[u * 2 + 1]);
            bool p0 = b0 >= TB[0], p1 = b1 >= TB[1], p2 = b2 >= TB[2], p3 = b3 >= TB[3];
            S1[0] += (m && p0) ? b0 : 0.f;   S2[0] += (m && !p0) ? d0 : 0.f;
            S1[1] += (m && p1) ? b1 : 0.f;   S2[1] += (m && !p1) ? d1 : 0.f;
            S1[2] += (m && p2) ? b2 : 0.f;   S2[2] += (m && !p2) ? d2 : 0.f;
            S1[3] += (m && p3) ? b3 : 0.f;   S2[3] += (m && !p3) ? d3 : 0.f;
        }
    }
    #pragma unroll
    for (int off = 1; off < 64; off <<= 1) {
        #pragma unroll
        for (int h = 0; h < 4; ++h) {
            S1[h] += __shfl_xor(S1[h], off);
            S2[h] += __shfl_xor(S2[h], off);
        }
    }
    if ((tid & 63) == 0) {
        #pragma unroll
        for (int h = 0; h < 4; ++h) { red[r][wv][h] = S1[h]; red[r][wv][4 + h] = S2[h]; }
    }
    __syncthreads();
    if (tid < 8) {
        int rr = tid >> 2, h = tid & 3;
        int ii = blockIdx.x * 2 + rr;
        float s1 = red[rr][0][h] + red[rr][1][h];
        float s2 = red[rr][0][4 + h] + red[rr][1][4 + h];
        float e = es[ii * NHEAD + h];
        float A = __expf(e), C = __expf(0.2f * e);
        float den = A * s1 + C * s2;
        float sc = den > 0.f ? 0.25f / den : 0.f;
        cfs[rr][h]     = A * sc;
        cfs[rr][4 + h] = C * sc;
    }
    __syncthreads();
    float cA[4], cC[4];
    #pragma unroll
    for (int h = 0; h < 4; ++h) { cA[h] = cfs[r][h]; cC[h] = cfs[r][4 + h]; }

    // ---- pass 2: write bf16 attn row (adj re-read hits L2/L3) ----
    unsigned short* orow = attn + (size_t)i * NN;
    #pragma unroll
    for (int it = 0; it < 8; ++it) {
        int jv = it * 128 + l;
        float4x av = arow4[jv];
        uint4 bu0 = B4[jv * 2], bu1 = B4[jv * 2 + 1];
        uint4 du0 = D4[jv * 2], du1 = D4[jv * 2 + 1];
        unsigned int bwv[8] = {bu0.x, bu0.y, bu0.z, bu0.w, bu1.x, bu1.y, bu1.z, bu1.w};
        unsigned int dwv[8] = {du0.x, du0.y, du0.z, du0.w, du1.x, du1.y, du1.z, du1.w};
        ushort4 o;
        unsigned short* op = (unsigned short*)&o;
        #pragma unroll
        for (int u = 0; u < 4; ++u) {
            float b0 = bflo(bwv[u * 2]), b1 = bfhi(bwv[u * 2]);
            float b2 = bflo(bwv[u * 2 + 1]), b3 = bfhi(bwv[u * 2 + 1]);
            float d0 = bflo(dwv[u * 2]), d1 = bfhi(dwv[u * 2]);
            float d2 = bflo(dwv[u * 2 + 1]), d3 = bfhi(dwv[u * 2 + 1]);
            float p;
            p  = (b0 >= TB[0]) ? cA[0] * b0 : cC[0] * d0;
            p += (b1 >= TB[1]) ? cA[1] * b1 : cC[1] * d1;
            p += (b2 >= TB[2]) ? cA[2] * b2 : cC[2] * d2;
            p += (b3 >= TB[3]) ? cA[3] * b3 : cC[3] * d3;
            op[u] = f2bf((av[u] > 0.1f) ? p : 0.f);
        }
        *(ushort4*)&orow[jv * 4] = o;
    }
}

// ============================================================
// K4: partials[s] = attn[:, ks] @ h[ks, :]  (bf16 MFMA, reg prefetch)
// grid (64 i-tiles, KSPLIT); 2 blocks/CU
// ============================================================
__global__ __launch_bounds__(256) void k_out_gemm(const unsigned short* __restrict__ attn,
                                                  const unsigned short* __restrict__ hT,
                                                  float* __restrict__ partials) {
    __shared__ __align__(16) unsigned short lds_a[64 * 40];
    __shared__ __align__(16) unsigned short lds_h[256 * 40];
    const int tid  = threadIdx.x;
    const int w    = tid >> 6;
    const int lane = tid & 63;
    const int lidx = lane & 15;
    const int quad = lane >> 4;
    const int i0    = blockIdx.x * 64;
    const int kbase = blockIdx.y * (NN / KSPLIT);
    const int srow = tid >> 3;      // 0..31
    const int skq  = tid & 7;

    float4x acc[4][4];
    #pragma unroll
    for (int a = 0; a < 4; ++a)
        #pragma unroll
        for (int b = 0; b < 4; ++b)
            acc[a][b] = (float4x){0.f, 0.f, 0.f, 0.f};

    ushort4 pa[2], ph[8];
    #pragma unroll
    for (int it = 0; it < 2; ++it)
        pa[it] = *(const ushort4*)&attn[(size_t)(i0 + it * 32 + srow) * NN + kbase + skq * 4];
    #pragma unroll
    for (int it = 0; it < 8; ++it)
        ph[it] = *(const ushort4*)&hT[(size_t)(it * 32 + srow) * NN + kbase + skq * 4];

    const int KSTEPS = (NN / KSPLIT) / 32;   // 16
    for (int ks = 0; ks < KSTEPS; ++ks) {
        __syncthreads();
        #pragma unroll
        for (int it = 0; it < 2; ++it)
            *(ushort4*)&lds_a[(it * 32 + srow) * 40 + skq * 4] = pa[it];
        #pragma unroll
        for (int it = 0; it < 8; ++it)
            *(ushort4*)&lds_h[(it * 32 + srow) * 40 + skq * 4] = ph[it];
        __syncthreads();
        if (ks < KSTEPS - 1) {
            const int ktn = kbase + (ks + 1) * 32;
            #pragma unroll
            for (int it = 0; it < 2; ++it)
                pa[it] = *(const ushort4*)&attn[(size_t)(i0 + it * 32 + srow) * NN + ktn + skq * 4];
            #pragma unroll
            for (int it = 0; it < 8; ++it)
                ph[it] = *(const ushort4*)&hT[(size_t)(it * 32 + srow) * NN + ktn + skq * 4];
        }
        short8x af[4], bfr[4];
        #pragma unroll
        for (int t = 0; t < 4; ++t) {
            af[t]  = *(const short8x*)&lds_a[(t * 16 + lidx) * 40 + quad * 8];
            bfr[t] = *(const short8x*)&lds_h[(w * 64 + t * 16 + lidx) * 40 + quad * 8];
        }
        #pragma unroll
        for (int it = 0; it < 4; ++it)
            #pragma unroll
            for (int nt = 0; nt < 4; ++nt)
                acc[it][nt] = __builtin_amdgcn_mfma_f32_16x16x32_bf16(
                    af[it], bfr[nt], acc[it][nt], 0, 0, 0);
    }
    float* pbase = partials + (size_t)blockIdx.y * NN * OUTF;
    #pragma unroll
    for (int it = 0; it < 4; ++it)
        #pragma unroll
        for (int nt = 0; nt < 4; ++nt)
            #pragma unroll
            for (int rr = 0; rr < 4; ++rr) {
                int row = i0 + it * 16 + quad * 4 + rr;
                int col = w * 64 + nt * 16 + lidx;
                pbase[(size_t)row * OUTF + col] = acc[it][nt][rr];
            }
}

// ============================================================
// K5: out = sum_s partials[s] + bias
// ============================================================
__global__ __launch_bounds__(256) void k_reduce_out(const float* __restrict__ partials,
                                                    const float* __restrict__ bias,
                                                    float* __restrict__ out) {
    const int i = blockIdx.x;
    const int n = threadIdx.x;
    float acc = bias[n];
    #pragma unroll
    for (int s = 0; s < KSPLIT; ++s)
        acc += partials[((size_t)s * NN + i) * OUTF + n];
    out[(size_t)i * OUTF + n] = acc;
}

// ============================================================
extern "C" void kernel_launch(void* const* d_in, const int* in_sizes, int n_in,
                              void* d_out, int out_size, void* d_ws, size_t ws_size,
                              hipStream_t stream) {
    const float* feat = (const float*)d_in[0];   // [4096,512]
    const float* adj  = (const float*)d_in[1];   // [4096,4096]
    const float* W    = (const float*)d_in[2];   // [256,512]
    const float* a    = (const float*)d_in[3];   // [4,128]
    const float* bias = (const float*)d_in[4];   // [256]
    float* out = (float*)d_out;                  // [4096,256] fp32

    char* ws = (char*)d_ws;
    float*          es    = (float*)(ws + 0);                        // 64 KiB
    unsigned short* Btb   = (unsigned short*)(ws + (64u << 10));     // 32 KiB
    unsigned short* Dtb   = (unsigned short*)(ws + (96u << 10));     // 32 KiB
    float*          wsrc  = (float*)(ws + (128u << 10));             // 8 KiB
    float*          wdst  = (float*)(ws + (160u << 10));             // 8 KiB
    unsigned short* hT    = (unsigned short*)(ws + (256u << 10));    // 2 MiB
    unsigned short* attn  = (unsigned short*)(ws + (2560u << 10));   // 32 MiB
    unsigned short* featb = (unsigned short*)(ws + (2560u << 10));   // 4 MiB (dead before attn written)
    unsigned short* Wb    = (unsigned short*)(ws + (6656u << 10));   // 256 KiB (dead before attn)
    float*          partials = (float*)(ws + (35328u << 10));        // 32 MiB

    k_prep      <<<2184,             256, 0, stream>>>(feat, W, a, featb, Wb, wsrc, wdst);
    k_edge      <<<256,              256, 0, stream>>>(feat, wsrc, wdst, es, Btb, Dtb);
    k_h_gemm    <<<dim3(4, 64),      256, 0, stream>>>(featb, Wb, hT);
    k_attn      <<<2048,             256, 0, stream>>>(adj, es, Btb, Dtb, attn);
    k_out_gemm  <<<dim3(64, KSPLIT), 256, 0, stream>>>(attn, hT, partials);
    k_reduce_out<<<NN,               256, 0, stream>>>(partials, bias, out);
}